// Round 1
// baseline (864.791 us; speedup 1.0000x reference)
//
#include <hip/hip_runtime.h>

#define NN 4096
#define NTHREADS 1024
#define NCHUNKS (NN / 64)

__global__ __launch_bounds__(NTHREADS)
void DistanceNMS_kernel(const float* __restrict__ peaks, float* __restrict__ out)
{
    __shared__ unsigned long long keys[NN];   // (~conf_bits)<<32 | orig_idx
    __shared__ float px[NN];
    __shared__ float py[NN];
    __shared__ unsigned char alive[NN];
    __shared__ float ckx[64];
    __shared__ float cky[64];
    __shared__ int ccount;

    const int tid = threadIdx.x;
    const int b = blockIdx.x;
    const float* bp = peaks + (size_t)b * NN * 3;
    float* bo = out + (size_t)b * NN * 3;

    // ---- load sort keys: ascending key == descending conf, ties by orig idx (stable) ----
    for (int j = tid; j < NN; j += NTHREADS) {
        float conf = bp[j * 3 + 2];
        unsigned bits = __float_as_uint(conf);   // conf >= 0 -> bits monotonic
        keys[j] = ((unsigned long long)(~bits) << 32) | (unsigned)j;
    }

    // ---- bitonic sort (ascending) in LDS ----
    for (unsigned k = 2; k <= NN; k <<= 1) {
        for (unsigned jj = k >> 1; jj > 0; jj >>= 1) {
            __syncthreads();
            for (unsigned i = tid; i < (unsigned)NN; i += NTHREADS) {
                unsigned ixj = i ^ jj;
                if (ixj > i) {
                    unsigned long long a = keys[i];
                    unsigned long long c = keys[ixj];
                    bool up = ((i & k) == 0);
                    if ((a > c) == up) { keys[i] = c; keys[ixj] = a; }
                }
            }
        }
    }
    __syncthreads();

    // ---- gather positions in sorted order ----
    for (int j = tid; j < NN; j += NTHREADS) {
        int oi = (int)(keys[j] & 0xFFFFFFFFu);
        px[j] = bp[oi * 3 + 0];
        py[j] = bp[oi * 3 + 1];
        alive[j] = 1;
    }

    // ---- chunked greedy NMS (exact greedy semantics) ----
    for (int c = 0; c < NCHUNKS; ++c) {
        const int base = c * 64;
        __syncthreads();   // prior apply done; safe to overwrite ckx/cky/alive[chunk]

        if (tid < 64) {
            const int j = base + tid;
            const float x = px[j];
            const float y = py[j];

            // whom-I-suppress mask within chunk (strictly later lanes, d2 < 16)
            unsigned long long smask = 0ull;
            #pragma unroll 8
            for (int i = 0; i < 64; ++i) {
                float xi = __shfl(x, i);
                float yi = __shfl(y, i);
                float dx = __fsub_rn(xi, x);
                float dy = __fsub_rn(yi, y);
                float d2 = __fadd_rn(__fmul_rn(dx, dx), __fmul_rn(dy, dy));
                if (i > tid && d2 < 16.0f) smask |= (1ull << i);
            }

            // serial greedy resolution (wave-uniform: keep identical in all lanes)
            unsigned long long keep = __ballot(alive[j] != 0);
            for (int i = 0; i < 64; ++i) {
                if ((keep >> i) & 1ull) {          // uniform branch
                    unsigned long long si = __shfl(smask, i);
                    keep &= ~si;
                }
            }

            const bool kept_me = (keep >> tid) & 1ull;
            alive[j] = kept_me ? 1 : 0;
            if (kept_me) {
                int slot = (int)__popcll(keep & ((1ull << tid) - 1ull));
                ckx[slot] = x;
                cky[slot] = y;
            }
            if (tid == 0) ccount = (int)__popcll(keep);
        }
        __syncthreads();

        // apply chunk's kept points to all later elements
        const int cnt = ccount;
        for (int j = base + 64 + tid; j < NN; j += NTHREADS) {
            if (alive[j]) {
                const float x = px[j];
                const float y = py[j];
                bool dead = false;
                for (int i = 0; i < cnt; ++i) {
                    float dx = __fsub_rn(x, ckx[i]);
                    float dy = __fsub_rn(y, cky[i]);
                    float d2 = __fadd_rn(__fmul_rn(dx, dx), __fmul_rn(dy, dy));
                    dead = dead || (d2 < 16.0f);
                }
                if (dead) alive[j] = 0;
            }
        }
    }
    __syncthreads();

    // ---- write output: sorted peaks masked by keep ----
    for (int j = tid; j < NN; j += NTHREADS) {
        unsigned long long key = keys[j];
        float conf = __uint_as_float(~(unsigned)(key >> 32));
        bool k = alive[j] != 0;
        bo[j * 3 + 0] = k ? px[j] : 0.0f;
        bo[j * 3 + 1] = k ? py[j] : 0.0f;
        bo[j * 3 + 2] = k ? conf : 0.0f;
    }
}

extern "C" void kernel_launch(void* const* d_in, const int* in_sizes, int n_in,
                              void* d_out, int out_size, void* d_ws, size_t ws_size,
                              hipStream_t stream) {
    const float* peaks = (const float*)d_in[0];
    float* out = (float*)d_out;
    const int B = in_sizes[0] / (NN * 3);
    DistanceNMS_kernel<<<B, NTHREADS, 0, stream>>>(peaks, out);
}

// Round 2
// 112.576 us; speedup vs baseline: 7.6818x; 7.6818x over previous
//
#include <hip/hip_runtime.h>

#define NN 4096
#define NT 1024
#define NCELL 64                 // 64x64 grid, cell size 8.0 (>= NMS radius 4)
#define NCELLS (NCELL * NCELL)

__global__ __launch_bounds__(NT)
void DistanceNMS_kernel(const float* __restrict__ peaks, float* __restrict__ out)
{
    __shared__ unsigned long long keys[NN];     // 32 KB : (~conf_bits)<<32 | orig_idx
    __shared__ float px[NN];                    // 16 KB
    __shared__ float py[NN];                    // 16 KB
    __shared__ unsigned cellcnt[NCELLS];        // 16 KB (atomic counters, then cursors)
    __shared__ unsigned cellstart[NCELLS + 1];  // 16 KB
    __shared__ unsigned short cellpts[NN];      //  8 KB (sorted-idx grouped by cell)
    __shared__ unsigned char state[NN];         //  4 KB (0=UNDET 1=KEPT 2=DEAD)
    __shared__ unsigned wavesum[16];
    __shared__ unsigned waveoff[16];

    const int tid = threadIdx.x;
    const int b = blockIdx.x;
    const float* bp = peaks + (size_t)b * NN * 3;
    float* bo = out + (size_t)b * NN * 3;

    // ---- sort keys: ascending == descending conf, stable ties by orig idx ----
    for (int j = tid; j < NN; j += NT) {
        unsigned bits = __float_as_uint(bp[j * 3 + 2]);   // conf >= 0
        keys[j] = ((unsigned long long)(~bits) << 32) | (unsigned)j;
    }
    for (int c = tid; c < NCELLS; c += NT) cellcnt[c] = 0;

    // ---- bitonic sort in LDS (validated bit-exact in round 0) ----
    for (unsigned k = 2; k <= NN; k <<= 1) {
        for (unsigned jj = k >> 1; jj > 0; jj >>= 1) {
            __syncthreads();
            for (unsigned i = tid; i < (unsigned)NN; i += NT) {
                unsigned ixj = i ^ jj;
                if (ixj > i) {
                    unsigned long long a = keys[i];
                    unsigned long long c = keys[ixj];
                    bool up = ((i & k) == 0);
                    if ((a > c) == up) { keys[i] = c; keys[ixj] = a; }
                }
            }
        }
    }
    __syncthreads();

    // ---- gather sorted positions + count cells ----
    for (int j = tid; j < NN; j += NT) {
        int oi = (int)(keys[j] & 0xFFFFFFFFu);
        float x = bp[oi * 3 + 0];
        float y = bp[oi * 3 + 1];
        px[j] = x; py[j] = y;
        state[j] = 0;
        int cx = min((int)(x * 0.125f), NCELL - 1);
        int cy = min((int)(y * 0.125f), NCELL - 1);
        atomicAdd(&cellcnt[cy * NCELL + cx], 1u);
    }
    __syncthreads();

    // ---- exclusive scan cellcnt -> cellstart ----
    {
        int t4 = tid * 4;
        unsigned c0 = cellcnt[t4], c1 = cellcnt[t4 + 1], c2 = cellcnt[t4 + 2], c3 = cellcnt[t4 + 3];
        unsigned tsum = c0 + c1 + c2 + c3;
        unsigned lane = tid & 63, wv = tid >> 6;
        unsigned sc = tsum;
        for (int off = 1; off < 64; off <<= 1) {
            unsigned n = __shfl_up(sc, off);
            if ((int)lane >= off) sc += n;
        }
        if (lane == 63) wavesum[wv] = sc;
        __syncthreads();
        if (tid == 0) {
            unsigned acc = 0;
            for (int i = 0; i < 16; ++i) { waveoff[i] = acc; acc += wavesum[i]; }
        }
        __syncthreads();
        unsigned base = waveoff[wv] + (sc - tsum);   // exclusive offset for this thread
        cellstart[t4 + 0] = base;
        cellstart[t4 + 1] = base + c0;
        cellstart[t4 + 2] = base + c0 + c1;
        cellstart[t4 + 3] = base + c0 + c1 + c2;
        if (tid == NT - 1) cellstart[NCELLS] = base + tsum;
    }
    __syncthreads();
    for (int c = tid; c < NCELLS; c += NT) cellcnt[c] = 0;   // reuse as cursors
    __syncthreads();

    // ---- scatter sorted indices into cell buckets ----
    for (int j = tid; j < NN; j += NT) {
        float x = px[j], y = py[j];
        int cx = min((int)(x * 0.125f), NCELL - 1);
        int cy = min((int)(y * 0.125f), NCELL - 1);
        int c = cy * NCELL + cx;
        unsigned p = cellstart[c] + atomicAdd(&cellcnt[c], 1u);
        cellpts[p] = (unsigned short)j;
    }
    __syncthreads();

    // ---- dataflow fixpoint == exact greedy NMS ----
    // state[j]: DEAD iff some earlier KEPT neighbor (d2<16); KEPT once all earlier
    // conflicting neighbors are determined DEAD. Monotone in-place updates are safe.
    while (true) {
        bool mine_undet = false;
        for (int j = tid; j < NN; j += NT) {
            if (state[j] != 0) continue;
            float x = px[j], y = py[j];
            int cx = min((int)(x * 0.125f), NCELL - 1);
            int cy = min((int)(y * 0.125f), NCELL - 1);
            float u = __fsub_rn(x, (float)(cx << 3));   // exact (Sterbenz)
            float v = __fsub_rn(y, (float)(cy << 3));
            int cx0 = (u < 4.0f) ? max(cx - 1, 0) : cx;
            int cy0 = (v < 4.0f) ? max(cy - 1, 0) : cy;
            bool any_kept = false, any_undet = false;
            #pragma unroll
            for (int dy = 0; dy < 2; ++dy) {
                int cyy = min(cy0 + dy, NCELL - 1);
                #pragma unroll
                for (int dxi = 0; dxi < 2; ++dxi) {
                    int cxx = min(cx0 + dxi, NCELL - 1);
                    int c = cyy * NCELL + cxx;
                    unsigned s = cellstart[c], e = cellstart[c + 1];
                    for (unsigned t = s; t < e; ++t) {
                        int m = cellpts[t];
                        if (m >= j) continue;            // only earlier (higher conf)
                        float dx = __fsub_rn(px[m], x);
                        float dyy = __fsub_rn(py[m], y);
                        float d2 = __fadd_rn(__fmul_rn(dx, dx), __fmul_rn(dyy, dyy));
                        if (d2 < 16.0f) {
                            unsigned char st = state[m];
                            if (st == 1) any_kept = true;
                            else if (st == 0) any_undet = true;
                        }
                    }
                }
            }
            if (any_kept) state[j] = 2;
            else if (!any_undet) state[j] = 1;
            else mine_undet = true;
        }
        if (__syncthreads_count(mine_undet ? 1 : 0) == 0) break;
    }

    // ---- write output: sorted peaks masked by keep ----
    for (int j = tid; j < NN; j += NT) {
        bool k = (state[j] == 1);
        float conf = __uint_as_float(~(unsigned)(keys[j] >> 32));
        bo[j * 3 + 0] = k ? px[j] : 0.0f;
        bo[j * 3 + 1] = k ? py[j] : 0.0f;
        bo[j * 3 + 2] = k ? conf : 0.0f;
    }
}

extern "C" void kernel_launch(void* const* d_in, const int* in_sizes, int n_in,
                              void* d_out, int out_size, void* d_ws, size_t ws_size,
                              hipStream_t stream) {
    const float* peaks = (const float*)d_in[0];
    float* out = (float*)d_out;
    const int B = in_sizes[0] / (NN * 3);
    DistanceNMS_kernel<<<B, NT, 0, stream>>>(peaks, out);
}

// Round 3
// 68.129 us; speedup vs baseline: 12.6935x; 1.6524x over previous
//
#include <hip/hip_runtime.h>

#define NN 4096
#define NT 1024
#define NCELL 64                 // 64x64 grid, cell size 8.0 (>= NMS radius 4)
#define NCELLS (NCELL * NCELL)

__global__ __launch_bounds__(NT)
void DistanceNMS_kernel(const float* __restrict__ peaks, float* __restrict__ out)
{
    // ---- LDS layout (~112 KB, heavily aliased across phases) ----
    __shared__ unsigned keyA[NN];            // 16K  sort key ping (final keys live here)
    __shared__ unsigned short payA[NN];      //  8K  payload ping; AFTER gather: worklist B
    __shared__ unsigned keyB[NN];            // 16K  sort key pong; AFTER sort: state[4K] + worklist A[8K]
    __shared__ unsigned short payB[NN];      //  8K  payload pong; AFTER sort: cellpts
    __shared__ unsigned hist[NN];            // 16K  radix hist (256 digits x 16 waves); then cell counters
    __shared__ unsigned cellstart[NCELLS+1]; // 16K
    __shared__ float px[NN];                 // 16K
    __shared__ float py[NN];                 // 16K
    __shared__ unsigned wavesum[16];
    __shared__ unsigned waveoff[16];
    __shared__ int wlcnt[2];

    const int tid = threadIdx.x;
    const int lane = tid & 63;
    const int wv = tid >> 6;
    const int b = blockIdx.x;
    const float* bp = peaks + (size_t)b * NN * 3;
    float* bo = out + (size_t)b * NN * 3;

    // ---- load keys: ascending ~conf_bits == descending conf; payload = orig idx ----
    for (int j = tid; j < NN; j += NT) {
        unsigned bits = __float_as_uint(bp[j * 3 + 2]);   // conf >= 0 -> monotonic bits
        keyA[j] = ~bits;
        payA[j] = (unsigned short)j;
    }

    // exclusive block scan of 4096 u32 in place (uniform call, contains barriers)
    auto scan4096 = [&](unsigned* arr, unsigned* dst, bool tail) {
        int t4 = tid << 2;
        unsigned c0 = arr[t4], c1 = arr[t4+1], c2 = arr[t4+2], c3 = arr[t4+3];
        unsigned tsum = c0 + c1 + c2 + c3;
        unsigned sc = tsum;
        for (int off = 1; off < 64; off <<= 1) {
            unsigned nn = __shfl_up(sc, off);
            if (lane >= off) sc += nn;
        }
        if (lane == 63) wavesum[wv] = sc;
        __syncthreads();
        if (tid == 0) {
            unsigned acc = 0;
            for (int i = 0; i < 16; ++i) { waveoff[i] = acc; acc += wavesum[i]; }
        }
        __syncthreads();
        unsigned base = waveoff[wv] + (sc - tsum);
        dst[t4+0] = base;
        dst[t4+1] = base + c0;
        dst[t4+2] = base + c0 + c1;
        dst[t4+3] = base + c0 + c1 + c2;
        if (tail && tid == NT - 1) dst[NN] = base + tsum;
    };

    // ---- 4-pass stable LSD radix sort (8-bit digits) ----
    {
        unsigned* srcK = keyA; unsigned short* srcP = payA;
        unsigned* dstK = keyB; unsigned short* dstP = payB;
        for (int pass = 0; pass < 4; ++pass) {
            const int shift = pass << 3;
            for (int f = tid; f < NN; f += NT) hist[f] = 0;
            __syncthreads();
            // count into hist[digit*16 + owner_wave], owner_wave = j>>8
            for (int j = tid; j < NN; j += NT) {
                unsigned d = (srcK[j] >> shift) & 255u;
                atomicAdd(&hist[(d << 4) | (unsigned)(j >> 8)], 1u);
            }
            __syncthreads();
            scan4096(hist, hist, false);
            __syncthreads();
            // stable scatter: wave w owns elements [w*256, w*256+256), 4 ordered groups
            for (int it = 0; it < 4; ++it) {
                int e = (wv << 8) + (it << 6) + lane;
                unsigned k = srcK[e];
                unsigned short p = srcP[e];
                unsigned d = (k >> shift) & 255u;
                unsigned long long mask = ~0ull;
                #pragma unroll
                for (int bit = 0; bit < 8; ++bit) {
                    unsigned long long bb = __ballot((d >> bit) & 1u);
                    mask &= ((d >> bit) & 1u) ? bb : ~bb;
                }
                int leader = __ffsll((unsigned long long)mask) - 1;
                int rank = __popcll(mask & ((1ull << lane) - 1ull));
                unsigned old = 0;
                if (lane == leader)
                    old = atomicAdd(&hist[(d << 4) | (unsigned)wv], (unsigned)__popcll(mask));
                old = __shfl(old, leader);
                dstK[old + rank] = k;
                dstP[old + rank] = p;
            }
            __syncthreads();
            unsigned* tk = srcK; srcK = dstK; dstK = tk;
            unsigned short* tp = srcP; srcP = dstP; dstP = tp;
        }
        // 4 passes -> sorted result back in keyA / payA
    }

    // ---- post-sort aliases ----
    unsigned char* state = (unsigned char*)keyB;                    // 4K of keyB
    unsigned short* wlA  = (unsigned short*)((char*)keyB + 8192);   // 8K of keyB
    unsigned short* wlB  = payA;                                    // reused after gather
    unsigned short* cellpts = payB;
    unsigned* cellcnt = hist;

    for (int c = tid; c < NCELLS; c += NT) cellcnt[c] = 0;
    if (tid == 0) { wlcnt[0] = 0; wlcnt[1] = 0; }
    __syncthreads();

    // ---- gather sorted positions + count cells ----
    for (int j = tid; j < NN; j += NT) {
        int oi = payA[j];
        float x = bp[oi * 3 + 0];
        float y = bp[oi * 3 + 1];
        px[j] = x; py[j] = y;
        state[j] = 0;
        int cx = min((int)(x * 0.125f), NCELL - 1);
        int cy = min((int)(y * 0.125f), NCELL - 1);
        atomicAdd(&cellcnt[cy * NCELL + cx], 1u);
    }
    __syncthreads();

    scan4096(cellcnt, cellstart, true);
    __syncthreads();
    for (int c = tid; c < NCELLS; c += NT) cellcnt[c] = 0;   // reuse as cursors
    __syncthreads();

    // ---- scatter sorted indices into cell buckets (payA no longer needed) ----
    for (int j = tid; j < NN; j += NT) {
        float x = px[j], y = py[j];
        int cx = min((int)(x * 0.125f), NCELL - 1);
        int cy = min((int)(y * 0.125f), NCELL - 1);
        int c = cy * NCELL + cx;
        unsigned p = cellstart[c] + atomicAdd(&cellcnt[c], 1u);
        cellpts[p] = (unsigned short)j;
    }
    __syncthreads();

    // ---- dataflow fixpoint == exact greedy NMS (monotone UNDET->KEPT/DEAD) ----
    auto eval = [&](int j) -> int {   // 0=undet 1=kept 2=dead
        float x = px[j], y = py[j];
        int cx = min((int)(x * 0.125f), NCELL - 1);
        int cy = min((int)(y * 0.125f), NCELL - 1);
        float u = __fsub_rn(x, (float)(cx << 3));   // exact (Sterbenz)
        float v = __fsub_rn(y, (float)(cy << 3));
        int cx0 = (u < 4.0f) ? max(cx - 1, 0) : cx;
        int cy0 = (v < 4.0f) ? max(cy - 1, 0) : cy;
        bool any_undet = false;
        #pragma unroll
        for (int dy = 0; dy < 2; ++dy) {
            int cyy = min(cy0 + dy, NCELL - 1);
            #pragma unroll
            for (int dxi = 0; dxi < 2; ++dxi) {
                int cxx = min(cx0 + dxi, NCELL - 1);
                int c = cyy * NCELL + cxx;
                unsigned s = cellstart[c], e = cellstart[c + 1];
                for (unsigned t = s; t < e; ++t) {
                    int m = cellpts[t];
                    if (m >= j) continue;            // only earlier (higher conf)
                    float dx = __fsub_rn(px[m], x);
                    float dyy = __fsub_rn(py[m], y);
                    float d2 = __fadd_rn(__fmul_rn(dx, dx), __fmul_rn(dyy, dyy));
                    if (d2 < 16.0f) {
                        unsigned char st = state[m];
                        if (st == 1) return 2;
                        if (st == 0) any_undet = true;
                    }
                }
            }
        }
        return any_undet ? 0 : 1;
    };

    // round 0: evaluate everyone, compact undet into worklist A
    for (int j = tid; j < NN; j += NT) {
        int r = eval(j);
        if (r) state[j] = (unsigned char)r;
        else wlA[atomicAdd(&wlcnt[0], 1)] = (unsigned short)j;
    }
    __syncthreads();

    int cur = 0;
    while (true) {
        int n = wlcnt[cur];
        if (n == 0) break;
        if (tid == 0) wlcnt[cur ^ 1] = 0;
        __syncthreads();
        unsigned short* src = cur ? wlB : wlA;
        unsigned short* dst = cur ? wlA : wlB;
        for (int i = tid; i < n; i += NT) {
            int j = src[i];
            int r = eval(j);
            if (r) state[j] = (unsigned char)r;
            else dst[atomicAdd(&wlcnt[cur ^ 1], 1)] = (unsigned short)j;
        }
        __syncthreads();
        cur ^= 1;
    }

    // ---- write output: sorted peaks masked by keep ----
    for (int j = tid; j < NN; j += NT) {
        bool k = (state[j] == 1);
        float conf = __uint_as_float(~keyA[j]);
        bo[j * 3 + 0] = k ? px[j] : 0.0f;
        bo[j * 3 + 1] = k ? py[j] : 0.0f;
        bo[j * 3 + 2] = k ? conf : 0.0f;
    }
}

extern "C" void kernel_launch(void* const* d_in, const int* in_sizes, int n_in,
                              void* d_out, int out_size, void* d_ws, size_t ws_size,
                              hipStream_t stream) {
    const float* peaks = (const float*)d_in[0];
    float* out = (float*)d_out;
    const int B = in_sizes[0] / (NN * 3);
    DistanceNMS_kernel<<<B, NT, 0, stream>>>(peaks, out);
}